// Round 10
// baseline (591.795 us; speedup 1.0000x reference)
//
#include <hip/hip_runtime.h>
#include <math.h>

// ---------------- problem constants ----------------
#define B_    8
#define H_    56
#define W_    56
#define HW_   3136
#define C0_   256
#define C1_   512
#define C2_   1024
#define DIN_  1794      // raw conv_w K (includes 2 coord cols, folded into epilogue)
#define KD_   1792      // descriptor K (GEMM K), 56 chunks of 32
#define KCP_  56        // phi K-chunks
#define DOUT_ 448
#define NCHP_ 28        // phi N-chunks (448/16)
#define NC_   3136      // centers
#define NCHD_ 196       // dist N-chunks (3136/16)
#define KCD_  14        // dist K-chunks (448/32)
#define DTS_  452       // LDS D-tile row stride (floats)
#define PCH_  28672     // phip chunk stride in shorts (in-place alias of desc pixels)

typedef __attribute__((ext_vector_type(8))) short bh8;
typedef __attribute__((ext_vector_type(4))) float f32x4;

__device__ __forceinline__ short f2bf(float f) {
  union { float f; unsigned u; } v; v.f = f;
  unsigned r = v.u + 0x7fffu + ((v.u >> 16) & 1u);
  return (short)(r >> 16);
}
__device__ __forceinline__ float bf2f(short s) {
  union { unsigned u; float f; } v; v.u = ((unsigned)(unsigned short)s) << 16;
  return v.f;
}

// ======== desc0: pool(p0) -> desc[:, 0:256], transposed, bf16 ========
__global__ __launch_bounds__(256) void desc0_kernel(const float* __restrict__ p0,
                                                    short* __restrict__ desc) {
  __shared__ float sv[64 * 57];
  const int c0 = blockIdx.x * 64, h = blockIdx.y, b = blockIdx.z;
  for (int item = threadIdx.x; item < 64 * 56; item += 256) {
    int x = item % 56, c = item / 56;
    const float* src = p0 + (((size_t)(b * C0_ + c0 + c)) * 56 + h) * 56 + x;
    float s = src[0];
    if (h > 0)  s += src[-56];
    if (h < 55) s += src[56];
    sv[c * 57 + x] = s;
  }
  __syncthreads();
  for (int item = threadIdx.x; item < 56 * 8; item += 256) {
    int g = item & 7, w = item >> 3;
    bh8 o;
#pragma unroll
    for (int j = 0; j < 8; ++j) {
      const float* s0 = sv + (g * 8 + j) * 57;
      float v = s0[w];
      if (w > 0)  v += s0[w - 1];
      if (w < 55) v += s0[w + 1];
      o[j] = f2bf(v * (1.0f / 9.0f));
    }
    size_t pid = (size_t)b * HW_ + h * 56 + w;
    *(bh8*)(desc + pid * KD_ + c0 + g * 8) = o;
  }
}

// ======== desc1: pool(p1)+bilinear x2 -> desc[:, 256:768] ========
__global__ __launch_bounds__(256) void desc1_kernel(const float* __restrict__ p1,
                                                    short* __restrict__ desc) {
  __shared__ float sv[2 * 64 * 29];
  const int c0 = blockIdx.x * 64, h = blockIdx.y, b = blockIdx.z;
  float sy = (h + 0.5f) * 0.5f - 0.5f;
  float fyf = floorf(sy);
  float fy = sy - fyf;
  int iy = (int)fyf;
  int pya = min(max(iy, 0), 27), pyb = min(max(iy + 1, 0), 27);
  for (int item = threadIdx.x; item < 64 * 2 * 28; item += 256) {
    int x = item % 28;
    int pr = (item / 28) & 1;
    int c = item / 56;
    int r = pr ? pyb : pya;
    const float* src = p1 + (((size_t)(b * C1_ + c0 + c)) * 28 + r) * 28 + x;
    float s = src[0];
    if (r > 0)  s += src[-28];
    if (r < 27) s += src[28];
    sv[pr * (64 * 29) + c * 29 + x] = s;
  }
  __syncthreads();
  for (int item = threadIdx.x; item < 56 * 8; item += 256) {
    int g = item & 7, w = item >> 3;
    float sx = (w + 0.5f) * 0.5f - 0.5f;
    float fxf = floorf(sx);
    float fx = sx - fxf;
    int ix = (int)fxf;
    int x0 = min(max(ix, 0), 27), x1 = min(max(ix + 1, 0), 27);
    bh8 o;
#pragma unroll
    for (int j = 0; j < 8; ++j) {
      const float* s0 = sv + (g * 8 + j) * 29;
      const float* s1 = s0 + 64 * 29;
      float p00 = s0[x0] + (x0 > 0 ? s0[x0 - 1] : 0.f) + (x0 < 27 ? s0[x0 + 1] : 0.f);
      float p01 = s0[x1] + (x1 > 0 ? s0[x1 - 1] : 0.f) + (x1 < 27 ? s0[x1 + 1] : 0.f);
      float p10 = s1[x0] + (x0 > 0 ? s1[x0 - 1] : 0.f) + (x0 < 27 ? s1[x0 + 1] : 0.f);
      float p11 = s1[x1] + (x1 > 0 ? s1[x1 - 1] : 0.f) + (x1 < 27 ? s1[x1 + 1] : 0.f);
      float top = p00 + fx * (p01 - p00);
      float bot = p10 + fx * (p11 - p10);
      o[j] = f2bf((top + fy * (bot - top)) * (1.0f / 9.0f));
    }
    size_t pid = (size_t)b * HW_ + h * 56 + w;
    *(bh8*)(desc + pid * KD_ + C0_ + c0 + g * 8) = o;
  }
}

// ======== desc2: pool(p2)+bilinear x4 -> desc[:, 768:1792] ========
__global__ __launch_bounds__(256) void desc2_kernel(const float* __restrict__ p2,
                                                    short* __restrict__ desc) {
  __shared__ float sv[2 * 64 * 15];
  const int c0 = blockIdx.x * 64, h = blockIdx.y, b = blockIdx.z;
  float sy = (h + 0.5f) * 0.25f - 0.5f;
  float fyf = floorf(sy);
  float fy = sy - fyf;
  int iy = (int)fyf;
  int pya = min(max(iy, 0), 13), pyb = min(max(iy + 1, 0), 13);
  for (int item = threadIdx.x; item < 64 * 2 * 14; item += 256) {
    int x = item % 14;
    int pr = (item / 14) & 1;
    int c = item / 28;
    int r = pr ? pyb : pya;
    const float* src = p2 + (((size_t)(b * C2_ + c0 + c)) * 14 + r) * 14 + x;
    float s = src[0];
    if (r > 0)  s += src[-14];
    if (r < 13) s += src[14];
    sv[pr * (64 * 15) + c * 15 + x] = s;
  }
  __syncthreads();
  for (int item = threadIdx.x; item < 56 * 8; item += 256) {
    int g = item & 7, w = item >> 3;
    float sx = (w + 0.5f) * 0.25f - 0.5f;
    float fxf = floorf(sx);
    float fx = sx - fxf;
    int ix = (int)fxf;
    int x0 = min(max(ix, 0), 13), x1 = min(max(ix + 1, 0), 13);
    bh8 o;
#pragma unroll
    for (int j = 0; j < 8; ++j) {
      const float* s0 = sv + (g * 8 + j) * 15;
      const float* s1 = s0 + 64 * 15;
      float p00 = s0[x0] + (x0 > 0 ? s0[x0 - 1] : 0.f) + (x0 < 13 ? s0[x0 + 1] : 0.f);
      float p01 = s0[x1] + (x1 > 0 ? s0[x1 - 1] : 0.f) + (x1 < 13 ? s0[x1 + 1] : 0.f);
      float p10 = s1[x0] + (x0 > 0 ? s1[x0 - 1] : 0.f) + (x0 < 13 ? s1[x0 + 1] : 0.f);
      float p11 = s1[x1] + (x1 > 0 ? s1[x1 - 1] : 0.f) + (x1 < 13 ? s1[x1 + 1] : 0.f);
      float top = p00 + fx * (p01 - p00);
      float bot = p10 + fx * (p11 - p10);
      o[j] = f2bf((top + fy * (bot - top)) * (1.0f / 9.0f));
    }
    size_t pid = (size_t)b * HW_ + h * 56 + w;
    *(bh8*)(desc + pid * KD_ + C0_ + C1_ + c0 + g * 8) = o;
  }
}

// ---------------- |c_j|^2 from bf16-rounded C ----------------
__global__ void cent2_kernel(const float* __restrict__ C, float* __restrict__ c2) {
  int j = blockIdx.x * blockDim.x + threadIdx.x;
  if (j >= NC_) return;
  float s = 0.f;
  for (int d = 0; d < DOUT_; ++d) {
    float v = bf2f(f2bf(C[(size_t)d * NC_ + j]));
    s = fmaf(v, v, s);
  }
  c2[j] = s;
}

// ---------------- pack C (K=448 x N=3136) into B-frag layout ----------------
__global__ void cpack_kernel(const float* __restrict__ C, short* __restrict__ Cpk) {
  int idx = blockIdx.x * 256 + threadIdx.x;       // NCHD_*KCD_*64 = 175616 exact
  int ln = idx & 63;
  int kc = (idx >> 6) % KCD_;
  int nc = idx / (KCD_ * 64);
  int n  = nc * 16 + (ln & 15);
  int k0 = kc * 32 + ((ln >> 4) << 3);
  bh8 o;
#pragma unroll
  for (int j = 0; j < 8; ++j) o[j] = f2bf(C[(size_t)(k0 + j) * NC_ + n]);
  *(bh8*)(Cpk + (size_t)idx * 8) = o;
}

// ---------------- pack W^T (K=1792 x N=448) into B-frag layout ----------------
__global__ void wpack_kernel(const float* __restrict__ W, short* __restrict__ Wpk) {
  int idx = blockIdx.x * 256 + threadIdx.x;       // NCHP_*KCP_*64 = 100352 exact
  int ln = idx & 63;
  int kc = (idx >> 6) % KCP_;
  int nc = idx / (KCP_ * 64);
  int n  = nc * 16 + (ln & 15);
  int k0 = kc * 32 + ((ln >> 4) << 3);
  bh8 o;
#pragma unroll
  for (int j = 0; j < 8; ++j) o[j] = f2bf(W[(size_t)n * DIN_ + k0 + j]);
  *(bh8*)(Wpk + (size_t)idx * 8) = o;
}

// ======== phi: A-frags direct from desc; bias+coords fused; in-place phipack ========
__global__ __launch_bounds__(256) void phi_mfma(
    const short* __restrict__ desc, const short* __restrict__ Wpk,
    const float* __restrict__ cw, const float* __restrict__ cb,
    short* __restrict__ phip /* aliases desc */) {
  __shared__ __align__(16) float Dt[16 * DTS_];   // 28.9 KB
  const int wv = threadIdx.x >> 6, ln = threadIdx.x & 63;
  const int pix0 = blockIdx.x * 32;
  const short* aptr = desc + ((size_t)(pix0 + (ln & 15))) * KD_ + ((ln >> 4) << 3);

  f32x4 acc[2][7];
#pragma unroll
  for (int rc = 0; rc < 2; ++rc)
#pragma unroll
    for (int i = 0; i < 7; ++i) acc[rc][i] = (f32x4){0.f, 0.f, 0.f, 0.f};

  const short* bbase = Wpk + (size_t)(wv * 7) * (KCP_ * 512) + ln * 8;
  for (int kc = 0; kc < KCP_; ++kc) {
    bh8 a0 = *(const bh8*)(aptr + kc * 32);
    bh8 a1 = *(const bh8*)(aptr + 16 * KD_ + kc * 32);
    const short* bp = bbase + kc * 512;
#pragma unroll
    for (int i = 0; i < 7; ++i) {
      bh8 bfr = *(const bh8*)(bp + (size_t)i * (KCP_ * 512));
      acc[0][i] = __builtin_amdgcn_mfma_f32_16x16x32_bf16(a0, bfr, acc[0][i], 0, 0, 0);
      acc[1][i] = __builtin_amdgcn_mfma_f32_16x16x32_bf16(a1, bfr, acc[1][i], 0, 0, 0);
    }
  }

  for (int rc = 0; rc < 2; ++rc) {
    __syncthreads();   // rc=0: all desc reads done; rc=1: all rc=0 repack reads done
#pragma unroll
    for (int i = 0; i < 7; ++i) {
      int col = (wv * 7 + i) * 16 + (ln & 15);
      float bias = cb[col];
      float wx = cw[(size_t)col * DIN_ + 1792];
      float wy = cw[(size_t)col * DIN_ + 1793];
#pragma unroll
      for (int r = 0; r < 4; ++r) {
        int row = ((ln >> 4) << 2) + r;
        int pid = pix0 + rc * 16 + row;
        int hw = pid % HW_;
        int hh = hw / 56, ww = hw % 56;
        float xx = (float)hh * (2.0f / 55.0f) - 1.0f;
        float yy = (float)ww * (2.0f / 55.0f) - 1.0f;
        Dt[row * DTS_ + col] = acc[rc][i][r] + bias + wx * xx + wy * yy;
      }
    }
    __syncthreads();
    short* op = phip + (size_t)(blockIdx.x * 2 + rc) * PCH_;
    for (int item = threadIdx.x; item < KCD_ * 64; item += 256) {
      int kc = item >> 6, lp = item & 63;
      int m = lp & 15, k0 = kc * 32 + ((lp >> 4) << 3);
      bh8 o;
#pragma unroll
      for (int j = 0; j < 8; ++j) o[j] = f2bf(Dt[m * DTS_ + k0 + j]);
      *(bh8*)(op + (size_t)item * 8) = o;
    }
  }
}

// ---------------- helpers shared by f2 / dist / merge ----------------
__device__ __forceinline__ float sumsq8(bh8 a, float s) {
#pragma unroll
  for (int j = 0; j < 8; ++j) { float v = bf2f(a[j]); s = fmaf(v, v, s); }
  return s;
}
__device__ __forceinline__ void insert3(float& t0, float& t1, float& t2, float v) {
  if (v < t2) {
    if (v < t1) {
      t2 = t1;
      if (v < t0) { t1 = t0; t0 = v; } else t1 = v;
    } else t2 = v;
  }
}
__device__ __forceinline__ void merge3(float& a0, float& a1, float& a2,
                                       float b0, float b1, float b2) {
  float lo0 = fminf(a0, b0), hi0 = fmaxf(a0, b0);
  float lo1 = fminf(a1, b1), hi1 = fmaxf(a1, b1);
  float lo2 = fminf(a2, b2);
  a0 = lo0;
  a1 = fminf(hi0, lo1);
  a2 = fminf(fmaxf(hi0, lo1), fminf(hi1, lo2));
}

// ---------------- f2: |phi_p|^2 per pixel (unchanged, passing) ----------------
__global__ __launch_bounds__(256) void f2_kernel(const short* __restrict__ phip,
                                                 float* __restrict__ f2g) {
  int p = blockIdx.x * 256 + threadIdx.x;   // 25088 exact
  const short* base = phip + (size_t)(p >> 4) * PCH_ + (p & 15) * 8;
  float s0 = 0.f, s1 = 0.f, s2 = 0.f, s3 = 0.f;
  for (int kc = 0; kc < KCD_; ++kc) {
    const short* b = base + kc * 512;
    s0 = sumsq8(*(const bh8*)(b), s0);
    s1 = sumsq8(*(const bh8*)(b + 128), s1);
    s2 = sumsq8(*(const bh8*)(b + 256), s2);
    s3 = sumsq8(*(const bh8*)(b + 384), s3);
  }
  f2g[p] = (s0 + s1) + (s2 + s3);
}

// ======== dist v18: v17 minus the spill — fence in TWO sequential groups of 7 ====
// R9: fence+TLP gave 318->255us BUT the 14-wide fence forced the allocator into
// scratch (VGPR=56, WRITE 76->271MB: ~195MB spill writeback ~= 60-80us of the
// 255). Fix: load A0-6, fence(7), MFMA 0-6, THEN load A7-13, fence(7), MFMA
// 7-13. Peak forced-live 28 VGPR (total ~75 < 128 cap) -> no spill; latency
// still amortized 7x per group; group-2 exposure hidden by 4-way TLP (proven
// R9). Ops and order identical -> same numerics.
__global__ __launch_bounds__(512, 4) void dist_nt(
    const short* __restrict__ phip, const short* __restrict__ Cpk,
    const float* __restrict__ c2g, const float* __restrict__ f2g,
    short* __restrict__ p49s /* aliases phip; writes land in chunk tails */) {
  __shared__ __align__(16) short Bsl[56 * 512];   // 56 KB: 4 nc x 14 kc x 1KB
  const int wv = threadIdx.x >> 6, ln = threadIdx.x & 63;
  // bijective XCD-chunked swizzle: nwg=4802 = 8*600+2
  const int orig = blockIdx.x;
  const int xcd = orig & 7, bi = orig >> 3;
  const int swz = (xcd < 2) ? xcd * 601 + bi : 1202 + (xcd - 2) * 600 + bi;
  const int nt = swz % 49;               // N-tile: centers [nt*64, nt*64+64)
  const int mg = swz / 49;               // M-group: chunks [mg*16, mg*16+16)
  const int nt4 = nt * 4;
  const int col = ln & 15, rb = (ln >> 4) << 2;

  // stage B-tile ONCE: 56 contiguous frags in Cpk; wave wv stages 7
  {
    const short* g_ = Cpk + (size_t)nt4 * (KCD_ * 512) + (size_t)(wv * 7) * 512 + ln * 8;
#pragma unroll
    for (int q = 0; q < 7; ++q)
      __builtin_amdgcn_global_load_lds(
          (const __attribute__((address_space(1))) unsigned int*)(g_ + q * 512),
          (__attribute__((address_space(3))) unsigned int*)(&Bsl[(wv * 7 + q) * 512]),
          16, 0, 0);
  }
  __syncthreads();   // one-time barrier: B-tile resident for the whole kernel

  const short* bl = (const short*)Bsl + ln * 8;
  // c2 values are block-invariant: load once
  const float c20 = c2g[(nt4 + 0) * 16 + col];
  const float c21 = c2g[(nt4 + 1) * 16 + col];
  const float c22 = c2g[(nt4 + 2) * 16 + col];
  const float c23 = c2g[(nt4 + 3) * 16 + col];
  const int cw = mg * 16 + wv * 2;       // this wave's 2 chunks

#pragma unroll 1
  for (int cc = 0; cc < 2; ++cc) {
    const int ch = cw + cc;
    const short* ap_ = phip + (size_t)ch * PCH_ + ln * 8;
    f32x4 a0 = {0.f, 0.f, 0.f, 0.f}, a1 = a0, a2 = a0, a3 = a0;
#define MK(kc) \
    a0 = __builtin_amdgcn_mfma_f32_16x16x32_bf16(A##kc, *(const bh8*)(bl + (0 * 14 + (kc)) * 512), a0, 0, 0, 0); \
    a1 = __builtin_amdgcn_mfma_f32_16x16x32_bf16(A##kc, *(const bh8*)(bl + (1 * 14 + (kc)) * 512), a1, 0, 0, 0); \
    a2 = __builtin_amdgcn_mfma_f32_16x16x32_bf16(A##kc, *(const bh8*)(bl + (2 * 14 + (kc)) * 512), a2, 0, 0, 0); \
    a3 = __builtin_amdgcn_mfma_f32_16x16x32_bf16(A##kc, *(const bh8*)(bl + (3 * 14 + (kc)) * 512), a3, 0, 0, 0);
    {   // ---- group 1: kc 0..6 ----
      bh8 A0 = *(const bh8*)(ap_ + 0 * 512), A1 = *(const bh8*)(ap_ + 1 * 512);
      bh8 A2 = *(const bh8*)(ap_ + 2 * 512), A3 = *(const bh8*)(ap_ + 3 * 512);
      bh8 A4 = *(const bh8*)(ap_ + 4 * 512), A5 = *(const bh8*)(ap_ + 5 * 512);
      bh8 A6 = *(const bh8*)(ap_ + 6 * 512);
      asm volatile("" : "+v"(A0), "+v"(A1), "+v"(A2), "+v"(A3), "+v"(A4),
                        "+v"(A5), "+v"(A6));
      MK(0) MK(1) MK(2) MK(3) MK(4) MK(5) MK(6)
    }
    {   // ---- group 2: kc 7..13 ----
      bh8 A7  = *(const bh8*)(ap_ +  7 * 512), A8  = *(const bh8*)(ap_ +  8 * 512);
      bh8 A9  = *(const bh8*)(ap_ +  9 * 512), A10 = *(const bh8*)(ap_ + 10 * 512);
      bh8 A11 = *(const bh8*)(ap_ + 11 * 512), A12 = *(const bh8*)(ap_ + 12 * 512);
      bh8 A13 = *(const bh8*)(ap_ + 13 * 512);
      asm volatile("" : "+v"(A7), "+v"(A8), "+v"(A9), "+v"(A10), "+v"(A11),
                        "+v"(A12), "+v"(A13));
      MK(7) MK(8) MK(9) MK(10) MK(11) MK(12) MK(13)
    }
#undef MK
    float fr0 = f2g[(size_t)ch * 16 + rb + 0];
    float fr1 = f2g[(size_t)ch * 16 + rb + 1];
    float fr2 = f2g[(size_t)ch * 16 + rb + 2];
    float fr3 = f2g[(size_t)ch * 16 + rb + 3];
    float t00 = 1e30f, t01 = 1e30f, t02 = 1e30f;
    float t10 = 1e30f, t11 = 1e30f, t12 = 1e30f;
    float t20 = 1e30f, t21 = 1e30f, t22 = 1e30f;
    float t30 = 1e30f, t31 = 1e30f, t32 = 1e30f;
    insert3(t00, t01, t02, fr0 + c20 - 2.0f * a0[0]);
    insert3(t10, t11, t12, fr1 + c20 - 2.0f * a0[1]);
    insert3(t20, t21, t22, fr2 + c20 - 2.0f * a0[2]);
    insert3(t30, t31, t32, fr3 + c20 - 2.0f * a0[3]);
    insert3(t00, t01, t02, fr0 + c21 - 2.0f * a1[0]);
    insert3(t10, t11, t12, fr1 + c21 - 2.0f * a1[1]);
    insert3(t20, t21, t22, fr2 + c21 - 2.0f * a1[2]);
    insert3(t30, t31, t32, fr3 + c21 - 2.0f * a1[3]);
    insert3(t00, t01, t02, fr0 + c22 - 2.0f * a2[0]);
    insert3(t10, t11, t12, fr1 + c22 - 2.0f * a2[1]);
    insert3(t20, t21, t22, fr2 + c22 - 2.0f * a2[2]);
    insert3(t30, t31, t32, fr3 + c22 - 2.0f * a2[3]);
    insert3(t00, t01, t02, fr0 + c23 - 2.0f * a3[0]);
    insert3(t10, t11, t12, fr1 + c23 - 2.0f * a3[1]);
    insert3(t20, t21, t22, fr2 + c23 - 2.0f * a3[2]);
    insert3(t30, t31, t32, fr3 + c23 - 2.0f * a3[3]);
#pragma unroll
    for (int m_ = 1; m_ <= 8; m_ <<= 1) {
      float b0, b1, b2;
      b0 = __shfl_xor(t00, m_, 64); b1 = __shfl_xor(t01, m_, 64); b2 = __shfl_xor(t02, m_, 64);
      merge3(t00, t01, t02, b0, b1, b2);
      b0 = __shfl_xor(t10, m_, 64); b1 = __shfl_xor(t11, m_, 64); b2 = __shfl_xor(t12, m_, 64);
      merge3(t10, t11, t12, b0, b1, b2);
      b0 = __shfl_xor(t20, m_, 64); b1 = __shfl_xor(t21, m_, 64); b2 = __shfl_xor(t22, m_, 64);
      merge3(t20, t21, t22, b0, b1, b2);
      b0 = __shfl_xor(t30, m_, 64); b1 = __shfl_xor(t31, m_, 64); b2 = __shfl_xor(t32, m_, 64);
      merge3(t30, t31, t32, b0, b1, b2);
    }
    if (col == 0) {
      float* o_ = (float*)(p49s + (size_t)ch * PCH_ + 7168);
      float* q_;
      q_ = o_ + ((size_t)nt * 16 + rb + 0) * 4; q_[0] = t00; q_[1] = t01; q_[2] = t02;
      q_ = o_ + ((size_t)nt * 16 + rb + 1) * 4; q_[0] = t10; q_[1] = t11; q_[2] = t12;
      q_ = o_ + ((size_t)nt * 16 + rb + 2) * 4; q_[0] = t20; q_[1] = t21; q_[2] = t22;
      q_ = o_ + ((size_t)nt * 16 + rb + 3) * 4; q_[0] = t30; q_[1] = t31; q_[2] = t32;
    }
  }
}

// ======== merge49: fold 49 partial triples per pixel (nt ascending), softmin ====
__global__ __launch_bounds__(256) void merge49_kernel(const short* __restrict__ p49s,
                                                      float* __restrict__ out) {
  int p = blockIdx.x * 256 + threadIdx.x;   // 25088 exact
  const float* base = (const float*)(p49s + (size_t)(p >> 4) * PCH_ + 7168);
  const int row = p & 15;
  float a0 = base[row * 4], a1 = base[row * 4 + 1], a2 = base[row * 4 + 2];
  for (int nt = 1; nt < 49; ++nt) {
    const float* q = base + ((size_t)nt * 16 + row) * 4;
    merge3(a0, a1, a2, q[0], q[1], q[2]);
  }
  float d0 = sqrtf(fmaxf(a0, 0.f));
  float d1 = sqrtf(fmaxf(a1, 0.f));
  float d2 = sqrtf(fmaxf(a2, 0.f));
  float s0 = 1.0f / (1.0f + expf(d0 - d1) + expf(d0 - d2));
  out[p] = s0 * d0;
}

// ---------------- launch ----------------
extern "C" void kernel_launch(void* const* d_in, const int* in_sizes, int n_in,
                              void* d_out, int out_size, void* d_ws, size_t ws_size,
                              hipStream_t stream) {
  const float* p0 = (const float*)d_in[0];
  const float* p1 = (const float*)d_in[1];
  const float* p2 = (const float*)d_in[2];
  const float* cw = (const float*)d_in[3];
  const float* cb = (const float*)d_in[4];
  const float* C  = (const float*)d_in[5];
  float* out = (float*)d_out;

  short* desc = (short*)d_ws;                                   // 44,957,696 shorts
  short* Cpk  = desc + (size_t)25088 * KD_;                     //  1,404,928 shorts
  short* Wpk  = Cpk + (size_t)NCHD_ * KCD_ * 512;               //    802,816 shorts
  float* c2   = (float*)(Wpk + (size_t)NCHP_ * KCP_ * 512);     //      3,136 floats
  float* f2g  = c2 + NC_;                                       //     25,088 floats

  desc0_kernel<<<dim3(4, 56, 8),  256, 0, stream>>>(p0, desc);
  desc1_kernel<<<dim3(8, 56, 8),  256, 0, stream>>>(p1, desc);
  desc2_kernel<<<dim3(16, 56, 8), 256, 0, stream>>>(p2, desc);
  cent2_kernel<<<(NC_ + 255) / 256, 256, 0, stream>>>(C, c2);
  cpack_kernel<<<NCHD_ * KCD_ * 64 / 256, 256, 0, stream>>>(C, Cpk);
  wpack_kernel<<<NCHP_ * KCP_ * 64 / 256, 256, 0, stream>>>(cw, Wpk);
  phi_mfma<<<25088 / 32, 256, 0, stream>>>(desc, Wpk, cw, cb, desc);
  f2_kernel<<<25088 / 256, 256, 0, stream>>>(desc, f2g);
  dist_nt<<<49 * 98, 512, 0, stream>>>(desc, Cpk, c2, f2g, desc);
  merge49_kernel<<<25088 / 256, 256, 0, stream>>>(desc, out);
}

// Round 11
// 582.756 us; speedup vs baseline: 1.0155x; 1.0155x over previous
//
#include <hip/hip_runtime.h>
#include <math.h>

// ---------------- problem constants ----------------
#define B_    8
#define H_    56
#define W_    56
#define HW_   3136
#define C0_   256
#define C1_   512
#define C2_   1024
#define DIN_  1794      // raw conv_w K (includes 2 coord cols, folded into epilogue)
#define KD_   1792      // descriptor K (GEMM K), 56 chunks of 32
#define KCP_  56        // phi K-chunks
#define DOUT_ 448
#define NCHP_ 28        // phi N-chunks (448/16)
#define NC_   3136      // centers
#define NCHD_ 196       // dist N-chunks (3136/16)
#define KCD_  14        // dist K-chunks (448/32)
#define DTS_  452       // LDS D-tile row stride (floats)
#define PCH_  28672     // phip chunk stride in shorts (in-place alias of desc pixels)

typedef __attribute__((ext_vector_type(8))) short bh8;
typedef __attribute__((ext_vector_type(4))) float f32x4;

__device__ __forceinline__ short f2bf(float f) {
  union { float f; unsigned u; } v; v.f = f;
  unsigned r = v.u + 0x7fffu + ((v.u >> 16) & 1u);
  return (short)(r >> 16);
}
__device__ __forceinline__ float bf2f(short s) {
  union { unsigned u; float f; } v; v.u = ((unsigned)(unsigned short)s) << 16;
  return v.f;
}

// ======== desc0: pool(p0) -> desc[:, 0:256], transposed, bf16 ========
__global__ __launch_bounds__(256) void desc0_kernel(const float* __restrict__ p0,
                                                    short* __restrict__ desc) {
  __shared__ float sv[64 * 57];
  const int c0 = blockIdx.x * 64, h = blockIdx.y, b = blockIdx.z;
  for (int item = threadIdx.x; item < 64 * 56; item += 256) {
    int x = item % 56, c = item / 56;
    const float* src = p0 + (((size_t)(b * C0_ + c0 + c)) * 56 + h) * 56 + x;
    float s = src[0];
    if (h > 0)  s += src[-56];
    if (h < 55) s += src[56];
    sv[c * 57 + x] = s;
  }
  __syncthreads();
  for (int item = threadIdx.x; item < 56 * 8; item += 256) {
    int g = item & 7, w = item >> 3;
    bh8 o;
#pragma unroll
    for (int j = 0; j < 8; ++j) {
      const float* s0 = sv + (g * 8 + j) * 57;
      float v = s0[w];
      if (w > 0)  v += s0[w - 1];
      if (w < 55) v += s0[w + 1];
      o[j] = f2bf(v * (1.0f / 9.0f));
    }
    size_t pid = (size_t)b * HW_ + h * 56 + w;
    *(bh8*)(desc + pid * KD_ + c0 + g * 8) = o;
  }
}

// ======== desc1: pool(p1)+bilinear x2 -> desc[:, 256:768] ========
__global__ __launch_bounds__(256) void desc1_kernel(const float* __restrict__ p1,
                                                    short* __restrict__ desc) {
  __shared__ float sv[2 * 64 * 29];
  const int c0 = blockIdx.x * 64, h = blockIdx.y, b = blockIdx.z;
  float sy = (h + 0.5f) * 0.5f - 0.5f;
  float fyf = floorf(sy);
  float fy = sy - fyf;
  int iy = (int)fyf;
  int pya = min(max(iy, 0), 27), pyb = min(max(iy + 1, 0), 27);
  for (int item = threadIdx.x; item < 64 * 2 * 28; item += 256) {
    int x = item % 28;
    int pr = (item / 28) & 1;
    int c = item / 56;
    int r = pr ? pyb : pya;
    const float* src = p1 + (((size_t)(b * C1_ + c0 + c)) * 28 + r) * 28 + x;
    float s = src[0];
    if (r > 0)  s += src[-28];
    if (r < 27) s += src[28];
    sv[pr * (64 * 29) + c * 29 + x] = s;
  }
  __syncthreads();
  for (int item = threadIdx.x; item < 56 * 8; item += 256) {
    int g = item & 7, w = item >> 3;
    float sx = (w + 0.5f) * 0.5f - 0.5f;
    float fxf = floorf(sx);
    float fx = sx - fxf;
    int ix = (int)fxf;
    int x0 = min(max(ix, 0), 27), x1 = min(max(ix + 1, 0), 27);
    bh8 o;
#pragma unroll
    for (int j = 0; j < 8; ++j) {
      const float* s0 = sv + (g * 8 + j) * 29;
      const float* s1 = s0 + 64 * 29;
      float p00 = s0[x0] + (x0 > 0 ? s0[x0 - 1] : 0.f) + (x0 < 27 ? s0[x0 + 1] : 0.f);
      float p01 = s0[x1] + (x1 > 0 ? s0[x1 - 1] : 0.f) + (x1 < 27 ? s0[x1 + 1] : 0.f);
      float p10 = s1[x0] + (x0 > 0 ? s1[x0 - 1] : 0.f) + (x0 < 27 ? s1[x0 + 1] : 0.f);
      float p11 = s1[x1] + (x1 > 0 ? s1[x1 - 1] : 0.f) + (x1 < 27 ? s1[x1 + 1] : 0.f);
      float top = p00 + fx * (p01 - p00);
      float bot = p10 + fx * (p11 - p10);
      o[j] = f2bf((top + fy * (bot - top)) * (1.0f / 9.0f));
    }
    size_t pid = (size_t)b * HW_ + h * 56 + w;
    *(bh8*)(desc + pid * KD_ + C0_ + c0 + g * 8) = o;
  }
}

// ======== desc2: pool(p2)+bilinear x4 -> desc[:, 768:1792] ========
__global__ __launch_bounds__(256) void desc2_kernel(const float* __restrict__ p2,
                                                    short* __restrict__ desc) {
  __shared__ float sv[2 * 64 * 15];
  const int c0 = blockIdx.x * 64, h = blockIdx.y, b = blockIdx.z;
  float sy = (h + 0.5f) * 0.25f - 0.5f;
  float fyf = floorf(sy);
  float fy = sy - fyf;
  int iy = (int)fyf;
  int pya = min(max(iy, 0), 13), pyb = min(max(iy + 1, 0), 13);
  for (int item = threadIdx.x; item < 64 * 2 * 14; item += 256) {
    int x = item % 14;
    int pr = (item / 14) & 1;
    int c = item / 28;
    int r = pr ? pyb : pya;
    const float* src = p2 + (((size_t)(b * C2_ + c0 + c)) * 14 + r) * 14 + x;
    float s = src[0];
    if (r > 0)  s += src[-14];
    if (r < 13) s += src[14];
    sv[pr * (64 * 15) + c * 15 + x] = s;
  }
  __syncthreads();
  for (int item = threadIdx.x; item < 56 * 8; item += 256) {
    int g = item & 7, w = item >> 3;
    float sx = (w + 0.5f) * 0.25f - 0.5f;
    float fxf = floorf(sx);
    float fx = sx - fxf;
    int ix = (int)fxf;
    int x0 = min(max(ix, 0), 13), x1 = min(max(ix + 1, 0), 13);
    bh8 o;
#pragma unroll
    for (int j = 0; j < 8; ++j) {
      const float* s0 = sv + (g * 8 + j) * 15;
      const float* s1 = s0 + 64 * 15;
      float p00 = s0[x0] + (x0 > 0 ? s0[x0 - 1] : 0.f) + (x0 < 13 ? s0[x0 + 1] : 0.f);
      float p01 = s0[x1] + (x1 > 0 ? s0[x1 - 1] : 0.f) + (x1 < 13 ? s0[x1 + 1] : 0.f);
      float p10 = s1[x0] + (x0 > 0 ? s1[x0 - 1] : 0.f) + (x0 < 13 ? s1[x0 + 1] : 0.f);
      float p11 = s1[x1] + (x1 > 0 ? s1[x1 - 1] : 0.f) + (x1 < 13 ? s1[x1 + 1] : 0.f);
      float top = p00 + fx * (p01 - p00);
      float bot = p10 + fx * (p11 - p10);
      o[j] = f2bf((top + fy * (bot - top)) * (1.0f / 9.0f));
    }
    size_t pid = (size_t)b * HW_ + h * 56 + w;
    *(bh8*)(desc + pid * KD_ + C0_ + C1_ + c0 + g * 8) = o;
  }
}

// ---------------- |c_j|^2 from bf16-rounded C ----------------
__global__ void cent2_kernel(const float* __restrict__ C, float* __restrict__ c2) {
  int j = blockIdx.x * blockDim.x + threadIdx.x;
  if (j >= NC_) return;
  float s = 0.f;
  for (int d = 0; d < DOUT_; ++d) {
    float v = bf2f(f2bf(C[(size_t)d * NC_ + j]));
    s = fmaf(v, v, s);
  }
  c2[j] = s;
}

// ---------------- pack C (K=448 x N=3136) into B-frag layout ----------------
__global__ void cpack_kernel(const float* __restrict__ C, short* __restrict__ Cpk) {
  int idx = blockIdx.x * 256 + threadIdx.x;       // NCHD_*KCD_*64 = 175616 exact
  int ln = idx & 63;
  int kc = (idx >> 6) % KCD_;
  int nc = idx / (KCD_ * 64);
  int n  = nc * 16 + (ln & 15);
  int k0 = kc * 32 + ((ln >> 4) << 3);
  bh8 o;
#pragma unroll
  for (int j = 0; j < 8; ++j) o[j] = f2bf(C[(size_t)(k0 + j) * NC_ + n]);
  *(bh8*)(Cpk + (size_t)idx * 8) = o;
}

// ---------------- pack W^T (K=1792 x N=448) into B-frag layout ----------------
__global__ void wpack_kernel(const float* __restrict__ W, short* __restrict__ Wpk) {
  int idx = blockIdx.x * 256 + threadIdx.x;       // NCHP_*KCP_*64 = 100352 exact
  int ln = idx & 63;
  int kc = (idx >> 6) % KCP_;
  int nc = idx / (KCP_ * 64);
  int n  = nc * 16 + (ln & 15);
  int k0 = kc * 32 + ((ln >> 4) << 3);
  bh8 o;
#pragma unroll
  for (int j = 0; j < 8; ++j) o[j] = f2bf(W[(size_t)n * DIN_ + k0 + j]);
  *(bh8*)(Wpk + (size_t)idx * 8) = o;
}

// ======== phi: A-frags direct from desc; bias+coords fused; in-place phipack ========
__global__ __launch_bounds__(256) void phi_mfma(
    const short* __restrict__ desc, const short* __restrict__ Wpk,
    const float* __restrict__ cw, const float* __restrict__ cb,
    short* __restrict__ phip /* aliases desc */) {
  __shared__ __align__(16) float Dt[16 * DTS_];   // 28.9 KB
  const int wv = threadIdx.x >> 6, ln = threadIdx.x & 63;
  const int pix0 = blockIdx.x * 32;
  const short* aptr = desc + ((size_t)(pix0 + (ln & 15))) * KD_ + ((ln >> 4) << 3);

  f32x4 acc[2][7];
#pragma unroll
  for (int rc = 0; rc < 2; ++rc)
#pragma unroll
    for (int i = 0; i < 7; ++i) acc[rc][i] = (f32x4){0.f, 0.f, 0.f, 0.f};

  const short* bbase = Wpk + (size_t)(wv * 7) * (KCP_ * 512) + ln * 8;
  for (int kc = 0; kc < KCP_; ++kc) {
    bh8 a0 = *(const bh8*)(aptr + kc * 32);
    bh8 a1 = *(const bh8*)(aptr + 16 * KD_ + kc * 32);
    const short* bp = bbase + kc * 512;
#pragma unroll
    for (int i = 0; i < 7; ++i) {
      bh8 bfr = *(const bh8*)(bp + (size_t)i * (KCP_ * 512));
      acc[0][i] = __builtin_amdgcn_mfma_f32_16x16x32_bf16(a0, bfr, acc[0][i], 0, 0, 0);
      acc[1][i] = __builtin_amdgcn_mfma_f32_16x16x32_bf16(a1, bfr, acc[1][i], 0, 0, 0);
    }
  }

  for (int rc = 0; rc < 2; ++rc) {
    __syncthreads();   // rc=0: all desc reads done; rc=1: all rc=0 repack reads done
#pragma unroll
    for (int i = 0; i < 7; ++i) {
      int col = (wv * 7 + i) * 16 + (ln & 15);
      float bias = cb[col];
      float wx = cw[(size_t)col * DIN_ + 1792];
      float wy = cw[(size_t)col * DIN_ + 1793];
#pragma unroll
      for (int r = 0; r < 4; ++r) {
        int row = ((ln >> 4) << 2) + r;
        int pid = pix0 + rc * 16 + row;
        int hw = pid % HW_;
        int hh = hw / 56, ww = hw % 56;
        float xx = (float)hh * (2.0f / 55.0f) - 1.0f;
        float yy = (float)ww * (2.0f / 55.0f) - 1.0f;
        Dt[row * DTS_ + col] = acc[rc][i][r] + bias + wx * xx + wy * yy;
      }
    }
    __syncthreads();
    short* op = phip + (size_t)(blockIdx.x * 2 + rc) * PCH_;
    for (int item = threadIdx.x; item < KCD_ * 64; item += 256) {
      int kc = item >> 6, lp = item & 63;
      int m = lp & 15, k0 = kc * 32 + ((lp >> 4) << 3);
      bh8 o;
#pragma unroll
      for (int j = 0; j < 8; ++j) o[j] = f2bf(Dt[m * DTS_ + k0 + j]);
      *(bh8*)(op + (size_t)item * 8) = o;
    }
  }
}

// ---------------- helpers shared by f2 / dist / merge ----------------
__device__ __forceinline__ float sumsq8(bh8 a, float s) {
#pragma unroll
  for (int j = 0; j < 8; ++j) { float v = bf2f(a[j]); s = fmaf(v, v, s); }
  return s;
}
__device__ __forceinline__ void insert3(float& t0, float& t1, float& t2, float v) {
  if (v < t2) {
    if (v < t1) {
      t2 = t1;
      if (v < t0) { t1 = t0; t0 = v; } else t1 = v;
    } else t2 = v;
  }
}
__device__ __forceinline__ void merge3(float& a0, float& a1, float& a2,
                                       float b0, float b1, float b2) {
  float lo0 = fminf(a0, b0), hi0 = fmaxf(a0, b0);
  float lo1 = fminf(a1, b1), hi1 = fmaxf(a1, b1);
  float lo2 = fminf(a2, b2);
  a0 = lo0;
  a1 = fminf(hi0, lo1);
  a2 = fminf(fmaxf(hi0, lo1), fminf(hi1, lo2));
}

// ---------------- f2: |phi_p|^2 per pixel (unchanged, passing) ----------------
__global__ __launch_bounds__(256) void f2_kernel(const short* __restrict__ phip,
                                                 float* __restrict__ f2g) {
  int p = blockIdx.x * 256 + threadIdx.x;   // 25088 exact
  const short* base = phip + (size_t)(p >> 4) * PCH_ + (p & 15) * 8;
  float s0 = 0.f, s1 = 0.f, s2 = 0.f, s3 = 0.f;
  for (int kc = 0; kc < KCD_; ++kc) {
    const short* b = base + kc * 512;
    s0 = sumsq8(*(const bh8*)(b), s0);
    s1 = sumsq8(*(const bh8*)(b + 128), s1);
    s2 = sumsq8(*(const bh8*)(b + 256), s2);
    s3 = sumsq8(*(const bh8*)(b + 384), s3);
  }
  f2g[p] = (s0 + s1) + (s2 + s3);
}

// ======== dist v19: v18 with the REAL spill fix — relax __launch_bounds__ ========
// R10 localized the spill: at (512,4) the allocator budgeted ~64 VGPR (52-56
// allocated + scratch), i.e. the 2nd launch_bounds arg behaved like CUDA
// minBlocksPerCU (4 blocks x 8 waves = 8 waves/SIMD -> 512/8 = 64 cap), NOT
// "waves per EU". Demand ~75-100 -> permanent spill regardless of fence shape.
// Fix: (512, 2) -> cap >= 128 under either semantics. Residency is LDS-limited
// at 2 blocks/CU (56 KB) either way, so occupancy is unchanged. Everything else
// byte-identical to v18 -> same numerics.
__global__ __launch_bounds__(512, 2) void dist_nt(
    const short* __restrict__ phip, const short* __restrict__ Cpk,
    const float* __restrict__ c2g, const float* __restrict__ f2g,
    short* __restrict__ p49s /* aliases phip; writes land in chunk tails */) {
  __shared__ __align__(16) short Bsl[56 * 512];   // 56 KB: 4 nc x 14 kc x 1KB
  const int wv = threadIdx.x >> 6, ln = threadIdx.x & 63;
  // bijective XCD-chunked swizzle: nwg=4802 = 8*600+2
  const int orig = blockIdx.x;
  const int xcd = orig & 7, bi = orig >> 3;
  const int swz = (xcd < 2) ? xcd * 601 + bi : 1202 + (xcd - 2) * 600 + bi;
  const int nt = swz % 49;               // N-tile: centers [nt*64, nt*64+64)
  const int mg = swz / 49;               // M-group: chunks [mg*16, mg*16+16)
  const int nt4 = nt * 4;
  const int col = ln & 15, rb = (ln >> 4) << 2;

  // stage B-tile ONCE: 56 contiguous frags in Cpk; wave wv stages 7
  {
    const short* g_ = Cpk + (size_t)nt4 * (KCD_ * 512) + (size_t)(wv * 7) * 512 + ln * 8;
#pragma unroll
    for (int q = 0; q < 7; ++q)
      __builtin_amdgcn_global_load_lds(
          (const __attribute__((address_space(1))) unsigned int*)(g_ + q * 512),
          (__attribute__((address_space(3))) unsigned int*)(&Bsl[(wv * 7 + q) * 512]),
          16, 0, 0);
  }
  __syncthreads();   // one-time barrier: B-tile resident for the whole kernel

  const short* bl = (const short*)Bsl + ln * 8;
  // c2 values are block-invariant: load once
  const float c20 = c2g[(nt4 + 0) * 16 + col];
  const float c21 = c2g[(nt4 + 1) * 16 + col];
  const float c22 = c2g[(nt4 + 2) * 16 + col];
  const float c23 = c2g[(nt4 + 3) * 16 + col];
  const int cw = mg * 16 + wv * 2;       // this wave's 2 chunks

#pragma unroll 1
  for (int cc = 0; cc < 2; ++cc) {
    const int ch = cw + cc;
    const short* ap_ = phip + (size_t)ch * PCH_ + ln * 8;
    f32x4 a0 = {0.f, 0.f, 0.f, 0.f}, a1 = a0, a2 = a0, a3 = a0;
#define MK(kc) \
    a0 = __builtin_amdgcn_mfma_f32_16x16x32_bf16(A##kc, *(const bh8*)(bl + (0 * 14 + (kc)) * 512), a0, 0, 0, 0); \
    a1 = __builtin_amdgcn_mfma_f32_16x16x32_bf16(A##kc, *(const bh8*)(bl + (1 * 14 + (kc)) * 512), a1, 0, 0, 0); \
    a2 = __builtin_amdgcn_mfma_f32_16x16x32_bf16(A##kc, *(const bh8*)(bl + (2 * 14 + (kc)) * 512), a2, 0, 0, 0); \
    a3 = __builtin_amdgcn_mfma_f32_16x16x32_bf16(A##kc, *(const bh8*)(bl + (3 * 14 + (kc)) * 512), a3, 0, 0, 0);
    {   // ---- group 1: kc 0..6 ----
      bh8 A0 = *(const bh8*)(ap_ + 0 * 512), A1 = *(const bh8*)(ap_ + 1 * 512);
      bh8 A2 = *(const bh8*)(ap_ + 2 * 512), A3 = *(const bh8*)(ap_ + 3 * 512);
      bh8 A4 = *(const bh8*)(ap_ + 4 * 512), A5 = *(const bh8*)(ap_ + 5 * 512);
      bh8 A6 = *(const bh8*)(ap_ + 6 * 512);
      asm volatile("" : "+v"(A0), "+v"(A1), "+v"(A2), "+v"(A3), "+v"(A4),
                        "+v"(A5), "+v"(A6));
      MK(0) MK(1) MK(2) MK(3) MK(4) MK(5) MK(6)
    }
    {   // ---- group 2: kc 7..13 ----
      bh8 A7  = *(const bh8*)(ap_ +  7 * 512), A8  = *(const bh8*)(ap_ +  8 * 512);
      bh8 A9  = *(const bh8*)(ap_ +  9 * 512), A10 = *(const bh8*)(ap_ + 10 * 512);
      bh8 A11 = *(const bh8*)(ap_ + 11 * 512), A12 = *(const bh8*)(ap_ + 12 * 512);
      bh8 A13 = *(const bh8*)(ap_ + 13 * 512);
      asm volatile("" : "+v"(A7), "+v"(A8), "+v"(A9), "+v"(A10), "+v"(A11),
                        "+v"(A12), "+v"(A13));
      MK(7) MK(8) MK(9) MK(10) MK(11) MK(12) MK(13)
    }
#undef MK
    float fr0 = f2g[(size_t)ch * 16 + rb + 0];
    float fr1 = f2g[(size_t)ch * 16 + rb + 1];
    float fr2 = f2g[(size_t)ch * 16 + rb + 2];
    float fr3 = f2g[(size_t)ch * 16 + rb + 3];
    float t00 = 1e30f, t01 = 1e30f, t02 = 1e30f;
    float t10 = 1e30f, t11 = 1e30f, t12 = 1e30f;
    float t20 = 1e30f, t21 = 1e30f, t22 = 1e30f;
    float t30 = 1e30f, t31 = 1e30f, t32 = 1e30f;
    insert3(t00, t01, t02, fr0 + c20 - 2.0f * a0[0]);
    insert3(t10, t11, t12, fr1 + c20 - 2.0f * a0[1]);
    insert3(t20, t21, t22, fr2 + c20 - 2.0f * a0[2]);
    insert3(t30, t31, t32, fr3 + c20 - 2.0f * a0[3]);
    insert3(t00, t01, t02, fr0 + c21 - 2.0f * a1[0]);
    insert3(t10, t11, t12, fr1 + c21 - 2.0f * a1[1]);
    insert3(t20, t21, t22, fr2 + c21 - 2.0f * a1[2]);
    insert3(t30, t31, t32, fr3 + c21 - 2.0f * a1[3]);
    insert3(t00, t01, t02, fr0 + c22 - 2.0f * a2[0]);
    insert3(t10, t11, t12, fr1 + c22 - 2.0f * a2[1]);
    insert3(t20, t21, t22, fr2 + c22 - 2.0f * a2[2]);
    insert3(t30, t31, t32, fr3 + c22 - 2.0f * a2[3]);
    insert3(t00, t01, t02, fr0 + c23 - 2.0f * a3[0]);
    insert3(t10, t11, t12, fr1 + c23 - 2.0f * a3[1]);
    insert3(t20, t21, t22, fr2 + c23 - 2.0f * a3[2]);
    insert3(t30, t31, t32, fr3 + c23 - 2.0f * a3[3]);
#pragma unroll
    for (int m_ = 1; m_ <= 8; m_ <<= 1) {
      float b0, b1, b2;
      b0 = __shfl_xor(t00, m_, 64); b1 = __shfl_xor(t01, m_, 64); b2 = __shfl_xor(t02, m_, 64);
      merge3(t00, t01, t02, b0, b1, b2);
      b0 = __shfl_xor(t10, m_, 64); b1 = __shfl_xor(t11, m_, 64); b2 = __shfl_xor(t12, m_, 64);
      merge3(t10, t11, t12, b0, b1, b2);
      b0 = __shfl_xor(t20, m_, 64); b1 = __shfl_xor(t21, m_, 64); b2 = __shfl_xor(t22, m_, 64);
      merge3(t20, t21, t22, b0, b1, b2);
      b0 = __shfl_xor(t30, m_, 64); b1 = __shfl_xor(t31, m_, 64); b2 = __shfl_xor(t32, m_, 64);
      merge3(t30, t31, t32, b0, b1, b2);
    }
    if (col == 0) {
      float* o_ = (float*)(p49s + (size_t)ch * PCH_ + 7168);
      float* q_;
      q_ = o_ + ((size_t)nt * 16 + rb + 0) * 4; q_[0] = t00; q_[1] = t01; q_[2] = t02;
      q_ = o_ + ((size_t)nt * 16 + rb + 1) * 4; q_[0] = t10; q_[1] = t11; q_[2] = t12;
      q_ = o_ + ((size_t)nt * 16 + rb + 2) * 4; q_[0] = t20; q_[1] = t21; q_[2] = t22;
      q_ = o_ + ((size_t)nt * 16 + rb + 3) * 4; q_[0] = t30; q_[1] = t31; q_[2] = t32;
    }
  }
}

// ======== merge49: fold 49 partial triples per pixel (nt ascending), softmin ====
__global__ __launch_bounds__(256) void merge49_kernel(const short* __restrict__ p49s,
                                                      float* __restrict__ out) {
  int p = blockIdx.x * 256 + threadIdx.x;   // 25088 exact
  const float* base = (const float*)(p49s + (size_t)(p >> 4) * PCH_ + 7168);
  const int row = p & 15;
  float a0 = base[row * 4], a1 = base[row * 4 + 1], a2 = base[row * 4 + 2];
  for (int nt = 1; nt < 49; ++nt) {
    const float* q = base + ((size_t)nt * 16 + row) * 4;
    merge3(a0, a1, a2, q[0], q[1], q[2]);
  }
  float d0 = sqrtf(fmaxf(a0, 0.f));
  float d1 = sqrtf(fmaxf(a1, 0.f));
  float d2 = sqrtf(fmaxf(a2, 0.f));
  float s0 = 1.0f / (1.0f + expf(d0 - d1) + expf(d0 - d2));
  out[p] = s0 * d0;
}

// ---------------- launch ----------------
extern "C" void kernel_launch(void* const* d_in, const int* in_sizes, int n_in,
                              void* d_out, int out_size, void* d_ws, size_t ws_size,
                              hipStream_t stream) {
  const float* p0 = (const float*)d_in[0];
  const float* p1 = (const float*)d_in[1];
  const float* p2 = (const float*)d_in[2];
  const float* cw = (const float*)d_in[3];
  const float* cb = (const float*)d_in[4];
  const float* C  = (const float*)d_in[5];
  float* out = (float*)d_out;

  short* desc = (short*)d_ws;                                   // 44,957,696 shorts
  short* Cpk  = desc + (size_t)25088 * KD_;                     //  1,404,928 shorts
  short* Wpk  = Cpk + (size_t)NCHD_ * KCD_ * 512;               //    802,816 shorts
  float* c2   = (float*)(Wpk + (size_t)NCHP_ * KCP_ * 512);     //      3,136 floats
  float* f2g  = c2 + NC_;                                       //     25,088 floats

  desc0_kernel<<<dim3(4, 56, 8),  256, 0, stream>>>(p0, desc);
  desc1_kernel<<<dim3(8, 56, 8),  256, 0, stream>>>(p1, desc);
  desc2_kernel<<<dim3(16, 56, 8), 256, 0, stream>>>(p2, desc);
  cent2_kernel<<<(NC_ + 255) / 256, 256, 0, stream>>>(C, c2);
  cpack_kernel<<<NCHD_ * KCD_ * 64 / 256, 256, 0, stream>>>(C, Cpk);
  wpack_kernel<<<NCHP_ * KCP_ * 64 / 256, 256, 0, stream>>>(cw, Wpk);
  phi_mfma<<<25088 / 32, 256, 0, stream>>>(desc, Wpk, cw, cb, desc);
  f2_kernel<<<25088 / 256, 256, 0, stream>>>(desc, f2g);
  dist_nt<<<49 * 98, 512, 0, stream>>>(desc, Cpk, c2, f2g, desc);
  merge49_kernel<<<25088 / 256, 256, 0, stream>>>(desc, out);
}